// Round 3
// baseline (192.966 us; speedup 1.0000x reference)
//
#include <hip/hip_runtime.h>
#include <math.h>

#define BLOCK 64
#define BATCH 16384
#define NDOF 7
#define ACTION_RANGE 50.0f
#define MAX_VEL 20.0f
#define HSTEP 0.1f

__device__ __forceinline__ void mat3_mul(float* C, const float* A, const float* B) {
#pragma unroll
  for (int r = 0; r < 3; r++) {
#pragma unroll
    for (int c = 0; c < 3; c++) {
      C[r*3+c] = A[r*3+0]*B[0*3+c] + A[r*3+1]*B[1*3+c] + A[r*3+2]*B[2*3+c];
    }
  }
}

__device__ __forceinline__ void mat3_vec(float* y, const float* A, const float* x) {
#pragma unroll
  for (int r = 0; r < 3; r++)
    y[r] = A[r*3+0]*x[0] + A[r*3+1]*x[1] + A[r*3+2]*x[2];
}

__device__ __forceinline__ void mat3T_vec(float* y, const float* A, const float* x) {
#pragma unroll
  for (int r = 0; r < 3; r++)
    y[r] = A[0*3+r]*x[0] + A[1*3+r]*x[1] + A[2*3+r]*x[2];
}

__device__ __forceinline__ void cross3(float* y, const float* a, const float* b) {
  y[0] = a[1]*b[2] - a[2]*b[1];
  y[1] = a[2]*b[0] - a[0]*b[2];
  y[2] = a[0]*b[1] - a[1]*b[0];
}

// R = I + s*W + (1-c)*W^2 ; p = (th*I + (1-c)*W + (th-s)*W^2) v
__device__ __forceinline__ void exp_se3(const float* A6, float th, float* R, float* p) {
  float w0 = A6[0], w1 = A6[1], w2 = A6[2];
  float s, c;
  sincosf(th, &s, &c);
  float omc = 1.0f - c, tms = th - s;
  float W[9]  = {0.f, -w2, w1,  w2, 0.f, -w0,  -w1, w0, 0.f};
  float W2[9];
  mat3_mul(W2, W, W);
#pragma unroll
  for (int k = 0; k < 9; k++) R[k] = s*W[k] + omc*W2[k];
  R[0] += 1.f; R[4] += 1.f; R[8] += 1.f;
  float G[9];
#pragma unroll
  for (int k = 0; k < 9; k++) G[k] = omc*W[k] + tms*W2[k];
  G[0] += th; G[4] += th; G[8] += th;
  mat3_vec(p, G, A6 + 3);
}

// python-style mod: a - floor(a/y)*y  (result in [0,y))
__device__ __forceinline__ float wrap_pi(float x) {
  const float PI_F  = 3.14159265358979323846f;
  const float TWO_PI = 6.28318530717958647692f;
  float a = x + PI_F;
  float r = a - floorf(a * (1.0f / TWO_PI)) * TWO_PI;
  return r - PI_F;
}

// __launch_bounds__(64, 1): 1 wave/EU minimum -> register allocator may use up
// to 512 VGPRs/wave (gfx950 unified file). R2 showed VGPR_Count=256 (default
// cap) + ~50 MB/dispatch scratch spill traffic = the whole kernel duration.
// Grid is exactly 1 wave per CU (256 blocks x 64 threads on 256 CUs), so fat
// waves cost zero occupancy here.
__global__ __launch_bounds__(BLOCK, 1) void arm_rk4_kernel(
    const float* __restrict__ g_state, const float* __restrict__ g_action,
    const float* __restrict__ g_M, const float* __restrict__ g_A,
    const float* __restrict__ g_G, const float* __restrict__ g_grav,
    float* __restrict__ g_out_state, float* __restrict__ g_out_ee)
{
  // ---- block-common model constants ----
  __shared__ float sMR[8][9];   // Mlist rotations (row-major)
  __shared__ float sMp[8][3];   // Mlist translations
  __shared__ float sIR[7][9];   // Minv rotations  (= R^T)
  __shared__ float sIp[7][3];   // Minv translations (= -R^T p)
  __shared__ float sA[7][6];    // screw axes (w normalized, v raw)
  __shared__ float sG[7][4];    // (Ix,Iy,Iz,m)
  __shared__ float sg[3];       // gravity
  // ---- per-thread scratch, [field][lane] layout (bank-conflict-free) ----
  __shared__ float sRB[7*18*BLOCK];  // per joint: R[9], B[9]  (AdT = [[R,0],[B,R]])
  __shared__ float sVV[7*12*BLOCK];  // per joint: Vw,Vv,Dw,Dv (or mass-column X)

  const int tid = threadIdx.x;

  if (tid < 8) {
    const float* Mi = g_M + tid*16;
    float a1[3] = {Mi[0], Mi[4], Mi[8]};
    float a2[3] = {Mi[1], Mi[5], Mi[9]};
    float p[3]  = {Mi[3], Mi[7], Mi[11]};
    float n1 = sqrtf(a1[0]*a1[0] + a1[1]*a1[1] + a1[2]*a1[2]);
    float b1[3] = {a1[0]/n1, a1[1]/n1, a1[2]/n1};
    float d = a2[0]*b1[0] + a2[1]*b1[1] + a2[2]*b1[2];
    float a2o[3] = {a2[0]-d*b1[0], a2[1]-d*b1[1], a2[2]-d*b1[2]};
    float n2 = sqrtf(a2o[0]*a2o[0] + a2o[1]*a2o[1] + a2o[2]*a2o[2]);
    float b2[3] = {a2o[0]/n2, a2o[1]/n2, a2o[2]/n2};
    float b3[3];
    cross3(b3, b1, b2);
    float R[9] = {b1[0], b2[0], b3[0],  b1[1], b2[1], b3[1],  b1[2], b2[2], b3[2]};
#pragma unroll
    for (int k = 0; k < 9; k++) sMR[tid][k] = R[k];
    sMp[tid][0] = p[0]; sMp[tid][1] = p[1]; sMp[tid][2] = p[2];
    if (tid < 7) {
#pragma unroll
      for (int r = 0; r < 3; r++)
#pragma unroll
        for (int c = 0; c < 3; c++) sIR[tid][r*3+c] = R[c*3+r];
#pragma unroll
      for (int r = 0; r < 3; r++)
        sIp[tid][r] = -(R[0*3+r]*p[0] + R[1*3+r]*p[1] + R[2*3+r]*p[2]);
      const float* Ar = g_A + tid*6;
      float nw = sqrtf(Ar[0]*Ar[0] + Ar[1]*Ar[1] + Ar[2]*Ar[2]);
      sA[tid][0] = Ar[0]/nw; sA[tid][1] = Ar[1]/nw; sA[tid][2] = Ar[2]/nw;
      sA[tid][3] = Ar[3];    sA[tid][4] = Ar[4];    sA[tid][5] = Ar[5];
      sG[tid][0] = fabsf(g_G[tid*4+0]);
      sG[tid][1] = fabsf(g_G[tid*4+1]);
      sG[tid][2] = fabsf(g_G[tid*4+2]);
      sG[tid][3] = fabsf(g_G[tid*4+3]);
    }
  }
  if (tid == 0) { sg[0] = g_grav[0]; sg[1] = g_grav[1]; sg[2] = g_grav[2]; }
  __syncthreads();

  const int b = blockIdx.x * BLOCK + tid;

  float q0[NDOF], dq0[NDOF], tau[NDOF];
#pragma unroll
  for (int i = 0; i < NDOF; i++) {
    q0[i]  = g_state[b*14 + i];
    dq0[i] = g_state[b*14 + 7 + i];
    tau[i] = g_action[b*7 + i] * ACTION_RANGE;
  }

  // ---- forward dynamics (derivs): qacc = M(q)^-1 (tau - bias(q,dq)) ----
  auto derivs = [&](const float* q, const float* dq, float* qacc) {
    // (1) adjoints AdT_i = [[R,0],[B,R]] for T = exp(-q_i [A_i]) Minv_i
#pragma unroll
    for (int i = 0; i < NDOF; i++) {
      float Ai[6];
#pragma unroll
      for (int k = 0; k < 6; k++) Ai[k] = sA[i][k];
      float Re[9], pe[3];
      exp_se3(Ai, -q[i], Re, pe);
      float IRl[9];
#pragma unroll
      for (int k = 0; k < 9; k++) IRl[k] = sIR[i][k];
      float Tr[9];
      mat3_mul(Tr, Re, IRl);
      float Ipl[3] = {sIp[i][0], sIp[i][1], sIp[i][2]};
      float Tp[3];
      mat3_vec(Tp, Re, Ipl);
      Tp[0] += pe[0]; Tp[1] += pe[1]; Tp[2] += pe[2];
      float Bm[9];
#pragma unroll
      for (int c = 0; c < 3; c++) {
        Bm[0*3+c] = -Tp[2]*Tr[1*3+c] + Tp[1]*Tr[2*3+c];
        Bm[1*3+c] =  Tp[2]*Tr[0*3+c] - Tp[0]*Tr[2*3+c];
        Bm[2*3+c] = -Tp[1]*Tr[0*3+c] + Tp[0]*Tr[1*3+c];
      }
#pragma unroll
      for (int k = 0; k < 9; k++) {
        sRB[(i*18 +     k)*BLOCK + tid] = Tr[k];
        sRB[(i*18 + 9 + k)*BLOCK + tid] = Bm[k];
      }
    }

    // (2) bias forward sweep: V, Vd per joint (ddq = 0, gravity on)
    float Vw[3] = {0,0,0}, Vv[3] = {0,0,0};
    float Dw[3] = {0,0,0}, Dv[3] = {-sg[0], -sg[1], -sg[2]};
#pragma unroll
    for (int i = 0; i < NDOF; i++) {
      float R[9], Bm[9];
#pragma unroll
      for (int k = 0; k < 9; k++) {
        R[k]  = sRB[(i*18 +     k)*BLOCK + tid];
        Bm[k] = sRB[(i*18 + 9 + k)*BLOCK + tid];
      }
      float tw[3], tv[3], t2[3];
      mat3_vec(tw, R, Vw);
      mat3_vec(tv, Bm, Vw);
      mat3_vec(t2, R, Vv);
      tv[0] += t2[0]; tv[1] += t2[1]; tv[2] += t2[2];
      float Aw[3] = {sA[i][0], sA[i][1], sA[i][2]};
      float Av[3] = {sA[i][3], sA[i][4], sA[i][5]};
      float dqi = dq[i];
#pragma unroll
      for (int k = 0; k < 3; k++) { Vw[k] = tw[k] + Aw[k]*dqi; Vv[k] = tv[k] + Av[k]*dqi; }
      mat3_vec(tw, R, Dw);
      mat3_vec(tv, Bm, Dw);
      mat3_vec(t2, R, Dv);
      tv[0] += t2[0]; tv[1] += t2[1]; tv[2] += t2[2];
      float c1[3], c2[3], c3[3];
      cross3(c1, Vw, Aw);   // ad(V) A: top = Vw x Aw
      cross3(c2, Vv, Aw);   //          bot = Vv x Aw + Vw x Av
      cross3(c3, Vw, Av);
#pragma unroll
      for (int k = 0; k < 3; k++) { Dw[k] = tw[k] + c1[k]*dqi; Dv[k] = tv[k] + (c2[k]+c3[k])*dqi; }
#pragma unroll
      for (int k = 0; k < 3; k++) {
        sVV[(i*12 +     k)*BLOCK + tid] = Vw[k];
        sVV[(i*12 + 3 + k)*BLOCK + tid] = Vv[k];
        sVV[(i*12 + 6 + k)*BLOCK + tid] = Dw[k];
        sVV[(i*12 + 9 + k)*BLOCK + tid] = Dv[k];
      }
    }

    // (3) bias backward sweep (ftip = 0)
    float bias[NDOF];
    {
      float Fw[3] = {0,0,0}, Fv[3] = {0,0,0};
#pragma unroll
      for (int ii = NDOF-1; ii >= 0; ii--) {
        if (ii < NDOF-1) {
          int j = ii + 1;
          float R[9], Bm[9];
#pragma unroll
          for (int k = 0; k < 9; k++) {
            R[k]  = sRB[(j*18 +     k)*BLOCK + tid];
            Bm[k] = sRB[(j*18 + 9 + k)*BLOCK + tid];
          }
          float nw[3], nv[3], t[3];
          mat3T_vec(nw, R, Fw);
          mat3T_vec(t, Bm, Fv);
          nw[0] += t[0]; nw[1] += t[1]; nw[2] += t[2];
          mat3T_vec(nv, R, Fv);
          Fw[0] = nw[0]; Fw[1] = nw[1]; Fw[2] = nw[2];
          Fv[0] = nv[0]; Fv[1] = nv[1]; Fv[2] = nv[2];
        }
        float Vwl[3], Vvl[3], Dwl[3], Dvl[3];
#pragma unroll
        for (int k = 0; k < 3; k++) {
          Vwl[k] = sVV[(ii*12 +     k)*BLOCK + tid];
          Vvl[k] = sVV[(ii*12 + 3 + k)*BLOCK + tid];
          Dwl[k] = sVV[(ii*12 + 6 + k)*BLOCK + tid];
          Dvl[k] = sVV[(ii*12 + 9 + k)*BLOCK + tid];
        }
        float gx = sG[ii][0], gy = sG[ii][1], gz = sG[ii][2], m = sG[ii][3];
        float GVw[3] = {gx*Vwl[0], gy*Vwl[1], gz*Vwl[2]};
        float GVv[3] = {m*Vvl[0],  m*Vvl[1],  m*Vvl[2]};
        float GDw[3] = {gx*Dwl[0], gy*Dwl[1], gz*Dwl[2]};
        float GDv[3] = {m*Dvl[0],  m*Dvl[1],  m*Dvl[2]};
        // F += G*Vd - ad(V)^T (G*V) = G*Vd + (Vw x GVw + Vv x GVv, Vw x GVv)
        float c1[3], c2[3], c3[3];
        cross3(c1, Vwl, GVw);
        cross3(c2, Vvl, GVv);
        cross3(c3, Vwl, GVv);
#pragma unroll
        for (int k = 0; k < 3; k++) { Fw[k] += GDw[k] + c1[k] + c2[k]; Fv[k] += GDv[k] + c3[k]; }
        bias[ii] = Fw[0]*sA[ii][0] + Fw[1]*sA[ii][1] + Fw[2]*sA[ii][2]
                 + Fv[0]*sA[ii][3] + Fv[1]*sA[ii][4] + Fv[2]*sA[ii][5];
      }
    }

    // (4) mass matrix, lower triangle only (dq=0,g=0,ftip=0 => V=0, ad terms vanish)
    float Lm[28];   // packed lower: idx(i,j) = i*(i+1)/2 + j
#pragma unroll
    for (int j = 0; j < NDOF; j++) {
      float Xw[3] = {sA[j][0], sA[j][1], sA[j][2]};
      float Xv[3] = {sA[j][3], sA[j][4], sA[j][5]};
#pragma unroll
      for (int k = 0; k < 3; k++) {
        sVV[(j*12 +     k)*BLOCK + tid] = Xw[k];
        sVV[(j*12 + 3 + k)*BLOCK + tid] = Xv[k];
      }
#pragma unroll
      for (int i = j+1; i < NDOF; i++) {
        float R[9], Bm[9];
#pragma unroll
        for (int k = 0; k < 9; k++) {
          R[k]  = sRB[(i*18 +     k)*BLOCK + tid];
          Bm[k] = sRB[(i*18 + 9 + k)*BLOCK + tid];
        }
        float tw[3], tv[3], t2[3];
        mat3_vec(tw, R, Xw);
        mat3_vec(tv, Bm, Xw);
        mat3_vec(t2, R, Xv);
#pragma unroll
        for (int k = 0; k < 3; k++) { Xw[k] = tw[k]; Xv[k] = tv[k] + t2[k]; }
#pragma unroll
        for (int k = 0; k < 3; k++) {
          sVV[(i*12 +     k)*BLOCK + tid] = Xw[k];
          sVV[(i*12 + 3 + k)*BLOCK + tid] = Xv[k];
        }
      }
      float Fw[3] = {0,0,0}, Fv[3] = {0,0,0};
#pragma unroll
      for (int i = NDOF-1; i >= j; i--) {
        if (i < NDOF-1) {
          int jn = i + 1;
          float R[9], Bm[9];
#pragma unroll
          for (int k = 0; k < 9; k++) {
            R[k]  = sRB[(jn*18 +     k)*BLOCK + tid];
            Bm[k] = sRB[(jn*18 + 9 + k)*BLOCK + tid];
          }
          float nw[3], nv[3], t[3];
          mat3T_vec(nw, R, Fw);
          mat3T_vec(t, Bm, Fv);
          nw[0] += t[0]; nw[1] += t[1]; nw[2] += t[2];
          mat3T_vec(nv, R, Fv);
          Fw[0] = nw[0]; Fw[1] = nw[1]; Fw[2] = nw[2];
          Fv[0] = nv[0]; Fv[1] = nv[1]; Fv[2] = nv[2];
        }
        float Xwl[3], Xvl[3];
#pragma unroll
        for (int k = 0; k < 3; k++) {
          Xwl[k] = sVV[(i*12 +     k)*BLOCK + tid];
          Xvl[k] = sVV[(i*12 + 3 + k)*BLOCK + tid];
        }
        Fw[0] += sG[i][0]*Xwl[0]; Fw[1] += sG[i][1]*Xwl[1]; Fw[2] += sG[i][2]*Xwl[2];
        Fv[0] += sG[i][3]*Xvl[0]; Fv[1] += sG[i][3]*Xvl[1]; Fv[2] += sG[i][3]*Xvl[2];
        Lm[i*(i+1)/2 + j] = Fw[0]*sA[i][0] + Fw[1]*sA[i][1] + Fw[2]*sA[i][2]
                          + Fv[0]*sA[i][3] + Fv[1]*sA[i][4] + Fv[2]*sA[i][5];
      }
    }

    // (5) Cholesky solve M qacc = tau - bias
    float y[NDOF];
#pragma unroll
    for (int i = 0; i < NDOF; i++) y[i] = tau[i] - bias[i];
#pragma unroll
    for (int k = 0; k < NDOF; k++) {
      float d = Lm[k*(k+1)/2 + k];
#pragma unroll
      for (int m2 = 0; m2 < k; m2++) { float l = Lm[k*(k+1)/2 + m2]; d -= l*l; }
      d = sqrtf(d);
      Lm[k*(k+1)/2 + k] = d;
      float inv = 1.0f / d;
#pragma unroll
      for (int i = k+1; i < NDOF; i++) {
        float s = Lm[i*(i+1)/2 + k];
#pragma unroll
        for (int m2 = 0; m2 < k; m2++) s -= Lm[i*(i+1)/2 + m2]*Lm[k*(k+1)/2 + m2];
        Lm[i*(i+1)/2 + k] = s * inv;
      }
    }
    // forward solve L y' = y (in place; reads already-solved y[m2<i])
#pragma unroll
    for (int i = 0; i < NDOF; i++) {
      float s = y[i];
#pragma unroll
      for (int m2 = 0; m2 < i; m2++) s -= Lm[i*(i+1)/2 + m2]*y[m2];
      y[i] = s / Lm[i*(i+1)/2 + i];
    }
    // back solve L^T x = y'  (reads already-solved qacc[m2>i])
#pragma unroll
    for (int i = NDOF-1; i >= 0; i--) {
      float s = y[i];
#pragma unroll
      for (int m2 = i+1; m2 < NDOF; m2++) s -= Lm[m2*(m2+1)/2 + i]*qacc[m2];
      qacc[i] = s / Lm[i*(i+1)/2 + i];
    }
  };

  // ---- RK4: 4 stages, single derivs body ----
  float qs[NDOF], dqs[NDOF], a[NDOF], accq[NDOF], accd[NDOF];
#pragma unroll
  for (int i = 0; i < NDOF; i++) { qs[i] = q0[i]; dqs[i] = dq0[i]; accq[i] = 0.f; accd[i] = 0.f; }

#pragma unroll 1
  for (int st = 0; st < 4; st++) {
    derivs(qs, dqs, a);
    float w = (st == 0 || st == 3) ? 1.0f : 2.0f;
#pragma unroll
    for (int i = 0; i < NDOF; i++) { accq[i] += w*dqs[i]; accd[i] += w*a[i]; }
    if (st < 3) {
      float c = (st == 2) ? HSTEP : 0.5f*HSTEP;
#pragma unroll
      for (int i = 0; i < NDOF; i++) qs[i] = q0[i] + c*dqs[i];
#pragma unroll
      for (int i = 0; i < NDOF; i++) dqs[i] = dq0[i] + c*a[i];
    }
  }

  const float h6 = HSTEP / 6.0f;
  float qf[NDOF], dqf[NDOF];
#pragma unroll
  for (int i = 0; i < NDOF; i++) {
    qf[i] = wrap_pi(q0[i] + h6*accq[i]);
    float v = dq0[i] + h6*accd[i];
    dqf[i] = fminf(fmaxf(v, -MAX_VEL), MAX_VEL);
  }

  // ---- FK in space for end-effector (x,y) ----
  float Tr[9] = {1,0,0, 0,1,0, 0,0,1};
  float Tp[3] = {0,0,0};
#pragma unroll
  for (int i = 0; i < NDOF; i++) {
    float MRl[9];
#pragma unroll
    for (int k = 0; k < 9; k++) MRl[k] = sMR[i][k];
    float Mpl[3] = {sMp[i][0], sMp[i][1], sMp[i][2]};
    float R1[9];
    mat3_mul(R1, Tr, MRl);
    float p1[3];
    mat3_vec(p1, Tr, Mpl);
    p1[0] += Tp[0]; p1[1] += Tp[1]; p1[2] += Tp[2];
    float Ai[6];
#pragma unroll
    for (int k = 0; k < 6; k++) Ai[k] = sA[i][k];
    float Re[9], pe[3];
    exp_se3(Ai, qf[i], Re, pe);
    mat3_mul(Tr, R1, Re);
    mat3_vec(Tp, R1, pe);
    Tp[0] += p1[0]; Tp[1] += p1[1]; Tp[2] += p1[2];
  }
  float Mp7[3] = {sMp[7][0], sMp[7][1], sMp[7][2]};
  float pf[3];
  mat3_vec(pf, Tr, Mp7);
  pf[0] += Tp[0]; pf[1] += Tp[1];

  // ---- stores ----
#pragma unroll
  for (int i = 0; i < NDOF; i++) {
    g_out_state[b*14 + i]     = qf[i];
    g_out_state[b*14 + 7 + i] = dqf[i];
  }
  g_out_ee[b*2 + 0] = pf[0];
  g_out_ee[b*2 + 1] = pf[1];
}

extern "C" void kernel_launch(void* const* d_in, const int* in_sizes, int n_in,
                              void* d_out, int out_size, void* d_ws, size_t ws_size,
                              hipStream_t stream) {
  const float* state  = (const float*)d_in[0];  // (16384,14)
  const float* action = (const float*)d_in[1];  // (16384,7)
  const float* M      = (const float*)d_in[2];  // (8,4,4)
  const float* A      = (const float*)d_in[3];  // (7,6)
  const float* G      = (const float*)d_in[4];  // (7,4)
  const float* grav   = (const float*)d_in[5];  // (3,)
  float* out_state = (float*)d_out;                       // (16384,14)
  float* out_ee    = (float*)d_out + (size_t)BATCH * 14;  // (16384,2)

  arm_rk4_kernel<<<BATCH / BLOCK, BLOCK, 0, stream>>>(
      state, action, M, A, G, grav, out_state, out_ee);
}

// Round 4
// 149.450 us; speedup vs baseline: 1.2912x; 1.2912x over previous
//
#include <hip/hip_runtime.h>
#include <math.h>

#define BLOCK 64
#define BATCH 16384
#define EPB 8      // elements per block (one wave = 8 elements x 8 roles)
#define EP 11      // element-dim stride (8 elems + pad) for per-element LDS
#define NDOF 7
#define ACTION_RANGE 50.0f
#define MAX_VEL 20.0f
#define HSTEP 0.1f

__device__ __forceinline__ void mat3_mul(float* C, const float* A, const float* B) {
#pragma unroll
  for (int r = 0; r < 3; r++) {
#pragma unroll
    for (int c = 0; c < 3; c++) {
      C[r*3+c] = A[r*3+0]*B[0*3+c] + A[r*3+1]*B[1*3+c] + A[r*3+2]*B[2*3+c];
    }
  }
}

__device__ __forceinline__ void mat3_vec(float* y, const float* A, const float* x) {
#pragma unroll
  for (int r = 0; r < 3; r++)
    y[r] = A[r*3+0]*x[0] + A[r*3+1]*x[1] + A[r*3+2]*x[2];
}

__device__ __forceinline__ void mat3T_vec(float* y, const float* A, const float* x) {
#pragma unroll
  for (int r = 0; r < 3; r++)
    y[r] = A[0*3+r]*x[0] + A[1*3+r]*x[1] + A[2*3+r]*x[2];
}

__device__ __forceinline__ void cross3(float* y, const float* a, const float* b) {
  y[0] = a[1]*b[2] - a[2]*b[1];
  y[1] = a[2]*b[0] - a[0]*b[2];
  y[2] = a[0]*b[1] - a[1]*b[0];
}

// R = I + s*W + (1-c)*W^2 ; p = (th*I + (1-c)*W + (th-s)*W^2) v
__device__ __forceinline__ void exp_se3(const float* A6, float th, float* R, float* p) {
  float w0 = A6[0], w1 = A6[1], w2 = A6[2];
  float s, c;
  sincosf(th, &s, &c);
  float omc = 1.0f - c, tms = th - s;
  float W[9]  = {0.f, -w2, w1,  w2, 0.f, -w0,  -w1, w0, 0.f};
  float W2[9];
  mat3_mul(W2, W, W);
#pragma unroll
  for (int k = 0; k < 9; k++) R[k] = s*W[k] + omc*W2[k];
  R[0] += 1.f; R[4] += 1.f; R[8] += 1.f;
  float G[9];
#pragma unroll
  for (int k = 0; k < 9; k++) G[k] = omc*W[k] + tms*W2[k];
  G[0] += th; G[4] += th; G[8] += th;
  mat3_vec(p, G, A6 + 3);
}

// python-style mod: a - floor(a/y)*y  (result in [0,y))
__device__ __forceinline__ float wrap_pi(float x) {
  const float PI_F   = 3.14159265358979323846f;
  const float TWO_PI = 6.28318530717958647692f;
  float a = x + PI_F;
  float r = a - floorf(a * (1.0f / TWO_PI)) * TWO_PI;
  return r - PI_F;
}

// 8 lanes per element: role r = lane&7, element slot e = lane>>3.
// R3 post-mortem: 1-thread-per-element needs ~430 live floats -> 256-VGPR arch
// cap -> ~46 MB/dispatch scratch-spill traffic = entire runtime. This layout
// keeps per-element 7-vectors one-component-per-lane (1 VGPR each), gives the
// mass matrix its natural 7-way column parallelism, and yields 2048 waves
// (8 waves/CU) for latency hiding.
__global__ __launch_bounds__(BLOCK, 2) void arm_rk4_kernel(
    const float* __restrict__ g_state, const float* __restrict__ g_action,
    const float* __restrict__ g_M, const float* __restrict__ g_A,
    const float* __restrict__ g_G, const float* __restrict__ g_grav,
    float* __restrict__ g_out_state, float* __restrict__ g_out_ee)
{
  __shared__ float sMR[8][9];
  __shared__ float sMp[8][3];
  __shared__ float sIR[7][9];
  __shared__ float sIp[7][3];
  __shared__ float sA[7][6];
  __shared__ float sG[7][4];
  __shared__ float sg[3];
  __shared__ float sRB[7*18*EP];
  __shared__ float tauL[NDOF*EP];
  __shared__ float dqsL[NDOF*EP];
  __shared__ float qaccL[NDOF*EP];
  __shared__ float qfL[NDOF*EP];
  __shared__ float MllL[28*EP];

  const int tid = threadIdx.x;
  const int e = tid >> 3;
  const int r = tid & 7;
  const int b = blockIdx.x * EPB + e;

  if (tid < 8) {
    const float* Mi = g_M + tid*16;
    float a1[3] = {Mi[0], Mi[4], Mi[8]};
    float a2[3] = {Mi[1], Mi[5], Mi[9]};
    float p[3]  = {Mi[3], Mi[7], Mi[11]};
    float n1 = sqrtf(a1[0]*a1[0] + a1[1]*a1[1] + a1[2]*a1[2]);
    float b1[3] = {a1[0]/n1, a1[1]/n1, a1[2]/n1};
    float d = a2[0]*b1[0] + a2[1]*b1[1] + a2[2]*b1[2];
    float a2o[3] = {a2[0]-d*b1[0], a2[1]-d*b1[1], a2[2]-d*b1[2]};
    float n2 = sqrtf(a2o[0]*a2o[0] + a2o[1]*a2o[1] + a2o[2]*a2o[2]);
    float b2[3] = {a2o[0]/n2, a2o[1]/n2, a2o[2]/n2};
    float b3[3];
    cross3(b3, b1, b2);
    float R[9] = {b1[0], b2[0], b3[0],  b1[1], b2[1], b3[1],  b1[2], b2[2], b3[2]};
#pragma unroll
    for (int k = 0; k < 9; k++) sMR[tid][k] = R[k];
    sMp[tid][0] = p[0]; sMp[tid][1] = p[1]; sMp[tid][2] = p[2];
    if (tid < 7) {
#pragma unroll
      for (int rr = 0; rr < 3; rr++)
#pragma unroll
        for (int cc = 0; cc < 3; cc++) sIR[tid][rr*3+cc] = R[cc*3+rr];
#pragma unroll
      for (int rr = 0; rr < 3; rr++)
        sIp[tid][rr] = -(R[0*3+rr]*p[0] + R[1*3+rr]*p[1] + R[2*3+rr]*p[2]);
      const float* Ar = g_A + tid*6;
      float nw = sqrtf(Ar[0]*Ar[0] + Ar[1]*Ar[1] + Ar[2]*Ar[2]);
      sA[tid][0] = Ar[0]/nw; sA[tid][1] = Ar[1]/nw; sA[tid][2] = Ar[2]/nw;
      sA[tid][3] = Ar[3];    sA[tid][4] = Ar[4];    sA[tid][5] = Ar[5];
      sG[tid][0] = fabsf(g_G[tid*4+0]);
      sG[tid][1] = fabsf(g_G[tid*4+1]);
      sG[tid][2] = fabsf(g_G[tid*4+2]);
      sG[tid][3] = fabsf(g_G[tid*4+3]);
    }
  }
  if (tid == 0) { sg[0] = g_grav[0]; sg[1] = g_grav[1]; sg[2] = g_grav[2]; }

  float q0 = 0.f, dq0 = 0.f, tau = 0.f, qs = 0.f, dqs = 0.f;
  float accq = 0.f, accd = 0.f;
  if (r < NDOF) {
    q0  = g_state[b*14 + r];
    dq0 = g_state[b*14 + 7 + r];
    tau = g_action[b*7 + r] * ACTION_RANGE;
    qs = q0; dqs = dq0;
    tauL[r*EP + e] = tau;
    dqsL[r*EP + e] = dq0;
  }
  __syncthreads();

#pragma unroll 1
  for (int st = 0; st < 4; st++) {
    float bias_reg[NDOF];   // r==7 lanes: carried B -> D within this stage

    // ---- (A) adjoint of joint r, lanes r<7 ----
    if (r < NDOF) {
      const int i = r;
      float Ai[6];
#pragma unroll
      for (int k = 0; k < 6; k++) Ai[k] = sA[i][k];
      float Re[9], pe[3];
      exp_se3(Ai, -qs, Re, pe);
      float IRl[9];
#pragma unroll
      for (int k = 0; k < 9; k++) IRl[k] = sIR[i][k];
      float Tr9[9];
      mat3_mul(Tr9, Re, IRl);
      float Ipl[3] = {sIp[i][0], sIp[i][1], sIp[i][2]};
      float Tp[3];
      mat3_vec(Tp, Re, Ipl);
      Tp[0] += pe[0]; Tp[1] += pe[1]; Tp[2] += pe[2];
      float Bm[9];
#pragma unroll
      for (int c = 0; c < 3; c++) {
        Bm[0*3+c] = -Tp[2]*Tr9[1*3+c] + Tp[1]*Tr9[2*3+c];
        Bm[1*3+c] =  Tp[2]*Tr9[0*3+c] - Tp[0]*Tr9[2*3+c];
        Bm[2*3+c] = -Tp[1]*Tr9[0*3+c] + Tp[0]*Tr9[1*3+c];
      }
#pragma unroll
      for (int k = 0; k < 9; k++) {
        sRB[(i*18 +     k)*EP + e] = Tr9[k];
        sRB[(i*18 + 9 + k)*EP + e] = Bm[k];
      }
    }
    __syncthreads();

    // ---- (B) bias sweep, lane r==7 ----
    if (r == NDOF) {
      float Vw[3] = {0,0,0}, Vv[3] = {0,0,0};
      float Dw[3] = {0,0,0}, Dv[3] = {-sg[0], -sg[1], -sg[2]};
      float Vh[NDOF][12];
#pragma unroll
      for (int i = 0; i < NDOF; i++) {
        float R[9], Bm[9];
#pragma unroll
        for (int k = 0; k < 9; k++) {
          R[k]  = sRB[(i*18 +     k)*EP + e];
          Bm[k] = sRB[(i*18 + 9 + k)*EP + e];
        }
        float tw[3], tv[3], t2[3];
        mat3_vec(tw, R, Vw);
        mat3_vec(tv, Bm, Vw);
        mat3_vec(t2, R, Vv);
        tv[0] += t2[0]; tv[1] += t2[1]; tv[2] += t2[2];
        float Aw[3] = {sA[i][0], sA[i][1], sA[i][2]};
        float Av[3] = {sA[i][3], sA[i][4], sA[i][5]};
        float dqi = dqsL[i*EP + e];
#pragma unroll
        for (int k = 0; k < 3; k++) { Vw[k] = tw[k] + Aw[k]*dqi; Vv[k] = tv[k] + Av[k]*dqi; }
        mat3_vec(tw, R, Dw);
        mat3_vec(tv, Bm, Dw);
        mat3_vec(t2, R, Dv);
        tv[0] += t2[0]; tv[1] += t2[1]; tv[2] += t2[2];
        float c1[3], c2[3], c3[3];
        cross3(c1, Vw, Aw);
        cross3(c2, Vv, Aw);
        cross3(c3, Vw, Av);
#pragma unroll
        for (int k = 0; k < 3; k++) { Dw[k] = tw[k] + c1[k]*dqi; Dv[k] = tv[k] + (c2[k]+c3[k])*dqi; }
#pragma unroll
        for (int k = 0; k < 3; k++) {
          Vh[i][k]   = Vw[k];
          Vh[i][3+k] = Vv[k];
          Vh[i][6+k] = Dw[k];
          Vh[i][9+k] = Dv[k];
        }
      }
      float Fw[3] = {0,0,0}, Fv[3] = {0,0,0};
#pragma unroll
      for (int ii = NDOF-1; ii >= 0; ii--) {
        if (ii < NDOF-1) {
          const int j = ii + 1;
          float R[9], Bm[9];
#pragma unroll
          for (int k = 0; k < 9; k++) {
            R[k]  = sRB[(j*18 +     k)*EP + e];
            Bm[k] = sRB[(j*18 + 9 + k)*EP + e];
          }
          float nw[3], nv[3], t[3];
          mat3T_vec(nw, R, Fw);
          mat3T_vec(t, Bm, Fv);
          nw[0] += t[0]; nw[1] += t[1]; nw[2] += t[2];
          mat3T_vec(nv, R, Fv);
          Fw[0] = nw[0]; Fw[1] = nw[1]; Fw[2] = nw[2];
          Fv[0] = nv[0]; Fv[1] = nv[1]; Fv[2] = nv[2];
        }
        float gx = sG[ii][0], gy = sG[ii][1], gz = sG[ii][2], m = sG[ii][3];
        float Vwl[3] = {Vh[ii][0], Vh[ii][1], Vh[ii][2]};
        float Vvl[3] = {Vh[ii][3], Vh[ii][4], Vh[ii][5]};
        float GVw[3] = {gx*Vwl[0], gy*Vwl[1], gz*Vwl[2]};
        float GVv[3] = {m*Vvl[0],  m*Vvl[1],  m*Vvl[2]};
        float GDw[3] = {gx*Vh[ii][6], gy*Vh[ii][7], gz*Vh[ii][8]};
        float GDv[3] = {m*Vh[ii][9],  m*Vh[ii][10], m*Vh[ii][11]};
        float c1[3], c2[3], c3[3];
        cross3(c1, Vwl, GVw);
        cross3(c2, Vvl, GVv);
        cross3(c3, Vwl, GVv);
#pragma unroll
        for (int k = 0; k < 3; k++) { Fw[k] += GDw[k] + c1[k] + c2[k]; Fv[k] += GDv[k] + c3[k]; }
        bias_reg[ii] = Fw[0]*sA[ii][0] + Fw[1]*sA[ii][1] + Fw[2]*sA[ii][2]
                     + Fv[0]*sA[ii][3] + Fv[1]*sA[ii][4] + Fv[2]*sA[ii][5];
      }
    }

    // ---- (C) mass-matrix column r, lanes r<7 ----
    if (r < NDOF) {
      float Ajw[3] = {sA[r][0], sA[r][1], sA[r][2]};
      float Ajv[3] = {sA[r][3], sA[r][4], sA[r][5]};
      float Xw[NDOF][3], Xv[NDOF][3];
#pragma unroll
      for (int k = 0; k < 3; k++) {
        Xw[0][k] = (r == 0) ? Ajw[k] : 0.f;
        Xv[0][k] = (r == 0) ? Ajv[k] : 0.f;
      }
#pragma unroll
      for (int i = 1; i < NDOF; i++) {
        float R[9], Bm[9];
#pragma unroll
        for (int k = 0; k < 9; k++) {
          R[k]  = sRB[(i*18 +     k)*EP + e];
          Bm[k] = sRB[(i*18 + 9 + k)*EP + e];
        }
        float tw[3], tv[3], t2[3];
        mat3_vec(tw, R,  Xw[i-1]);
        mat3_vec(tv, Bm, Xw[i-1]);
        mat3_vec(t2, R,  Xv[i-1]);
#pragma unroll
        for (int k = 0; k < 3; k++) {
          float w_ = tw[k];
          float v_ = tv[k] + t2[k];
          Xw[i][k] = (i == r) ? Ajw[k] : w_;
          Xv[i][k] = (i == r) ? Ajv[k] : v_;
        }
      }
      float Fw[3] = {0,0,0}, Fv[3] = {0,0,0};
#pragma unroll
      for (int i = NDOF-1; i >= 0; i--) {
        if (i < NDOF-1) {
          const int jn = i + 1;
          float R[9], Bm[9];
#pragma unroll
          for (int k = 0; k < 9; k++) {
            R[k]  = sRB[(jn*18 +     k)*EP + e];
            Bm[k] = sRB[(jn*18 + 9 + k)*EP + e];
          }
          float nw[3], nv[3], t[3];
          mat3T_vec(nw, R, Fw);
          mat3T_vec(t, Bm, Fv);
          nw[0] += t[0]; nw[1] += t[1]; nw[2] += t[2];
          mat3T_vec(nv, R, Fv);
          Fw[0] = nw[0]; Fw[1] = nw[1]; Fw[2] = nw[2];
          Fv[0] = nv[0]; Fv[1] = nv[1]; Fv[2] = nv[2];
        }
        Fw[0] += sG[i][0]*Xw[i][0]; Fw[1] += sG[i][1]*Xw[i][1]; Fw[2] += sG[i][2]*Xw[i][2];
        Fv[0] += sG[i][3]*Xv[i][0]; Fv[1] += sG[i][3]*Xv[i][1]; Fv[2] += sG[i][3]*Xv[i][2];
        float Mij = Fw[0]*sA[i][0] + Fw[1]*sA[i][1] + Fw[2]*sA[i][2]
                  + Fv[0]*sA[i][3] + Fv[1]*sA[i][4] + Fv[2]*sA[i][5];
        if (i >= r) MllL[(i*(i+1)/2 + r)*EP + e] = Mij;
      }
    }
    __syncthreads();

    // ---- (D) Cholesky solve, lane r==7 ----
    if (r == NDOF) {
      float Lm[28];
#pragma unroll
      for (int idx = 0; idx < 28; idx++) Lm[idx] = MllL[idx*EP + e];
      float y[NDOF];
#pragma unroll
      for (int i = 0; i < NDOF; i++) y[i] = tauL[i*EP + e] - bias_reg[i];
#pragma unroll
      for (int k = 0; k < NDOF; k++) {
        float d = Lm[k*(k+1)/2 + k];
#pragma unroll
        for (int m2 = 0; m2 < k; m2++) { float l = Lm[k*(k+1)/2 + m2]; d -= l*l; }
        d = sqrtf(d);
        Lm[k*(k+1)/2 + k] = d;
        float inv = 1.0f / d;
#pragma unroll
        for (int i = k+1; i < NDOF; i++) {
          float s = Lm[i*(i+1)/2 + k];
#pragma unroll
          for (int m2 = 0; m2 < k; m2++) s -= Lm[i*(i+1)/2 + m2]*Lm[k*(k+1)/2 + m2];
          Lm[i*(i+1)/2 + k] = s * inv;
        }
      }
#pragma unroll
      for (int i = 0; i < NDOF; i++) {
        float s = y[i];
#pragma unroll
        for (int m2 = 0; m2 < i; m2++) s -= Lm[i*(i+1)/2 + m2]*y[m2];
        y[i] = s / Lm[i*(i+1)/2 + i];
      }
      float qac[NDOF];
#pragma unroll
      for (int i = NDOF-1; i >= 0; i--) {
        float s = y[i];
#pragma unroll
        for (int m2 = i+1; m2 < NDOF; m2++) s -= Lm[m2*(m2+1)/2 + i]*qac[m2];
        qac[i] = s / Lm[i*(i+1)/2 + i];
      }
#pragma unroll
      for (int i = 0; i < NDOF; i++) qaccL[i*EP + e] = qac[i];
    }
    __syncthreads();

    // ---- (E) RK4 stage update, lanes r<7 ----
    if (r < NDOF) {
      float a = qaccL[r*EP + e];
      float w = (st == 0 || st == 3) ? 1.0f : 2.0f;
      accq += w * dqs;
      accd += w * a;
      if (st < 3) {
        float c = (st == 2) ? HSTEP : 0.5f*HSTEP;
        qs  = q0  + c * dqs;
        dqs = dq0 + c * a;
        dqsL[r*EP + e] = dqs;
      }
    }
    // no barrier needed: next stage's post-(A) barrier orders dqsL (E write ->
    // B read) and qaccL (E read -> next D write); sRB WAR is covered by the
    // post-(C) barrier before this stage's D.
  }

  const float h6 = HSTEP / 6.0f;
  if (r < NDOF) {
    float qf = wrap_pi(q0 + h6*accq);
    float v  = dq0 + h6*accd;
    float dqf = fminf(fmaxf(v, -MAX_VEL), MAX_VEL);
    qfL[r*EP + e] = qf;
    g_out_state[b*14 + r]     = qf;
    g_out_state[b*14 + 7 + r] = dqf;
  }
  __syncthreads();

  if (r == NDOF) {
    float Tr9[9] = {1,0,0, 0,1,0, 0,0,1};
    float Tp[3] = {0,0,0};
#pragma unroll
    for (int i = 0; i < NDOF; i++) {
      float MRl[9];
#pragma unroll
      for (int k = 0; k < 9; k++) MRl[k] = sMR[i][k];
      float Mpl[3] = {sMp[i][0], sMp[i][1], sMp[i][2]};
      float R1[9];
      mat3_mul(R1, Tr9, MRl);
      float p1[3];
      mat3_vec(p1, Tr9, Mpl);
      p1[0] += Tp[0]; p1[1] += Tp[1]; p1[2] += Tp[2];
      float Ai[6];
#pragma unroll
      for (int k = 0; k < 6; k++) Ai[k] = sA[i][k];
      float Re[9], pe[3];
      exp_se3(Ai, qfL[i*EP + e], Re, pe);
      mat3_mul(Tr9, R1, Re);
      mat3_vec(Tp, R1, pe);
      Tp[0] += p1[0]; Tp[1] += p1[1]; Tp[2] += p1[2];
    }
    float Mp7[3] = {sMp[7][0], sMp[7][1], sMp[7][2]};
    float pf[3];
    mat3_vec(pf, Tr9, Mp7);
    g_out_ee[b*2 + 0] = pf[0] + Tp[0];
    g_out_ee[b*2 + 1] = pf[1] + Tp[1];
  }
}

extern "C" void kernel_launch(void* const* d_in, const int* in_sizes, int n_in,
                              void* d_out, int out_size, void* d_ws, size_t ws_size,
                              hipStream_t stream) {
  const float* state  = (const float*)d_in[0];  // (16384,14)
  const float* action = (const float*)d_in[1];  // (16384,7)
  const float* M      = (const float*)d_in[2];  // (8,4,4)
  const float* A      = (const float*)d_in[3];  // (7,6)
  const float* G      = (const float*)d_in[4];  // (7,4)
  const float* grav   = (const float*)d_in[5];  // (3,)
  float* out_state = (float*)d_out;                       // (16384,14)
  float* out_ee    = (float*)d_out + (size_t)BATCH * 14;  // (16384,2)

  arm_rk4_kernel<<<BATCH / EPB, BLOCK, 0, stream>>>(
      state, action, M, A, G, grav, out_state, out_ee);
}

// Round 5
// 145.168 us; speedup vs baseline: 1.3293x; 1.0295x over previous
//
#include <hip/hip_runtime.h>
#include <math.h>

#define BLOCK 64
#define BATCH 16384
#define EPB 8      // elements per block (one wave = 8 elements x 8 roles)
#define EP 11      // element-dim stride (8 elems + pad) for per-element LDS
#define NDOF 7
#define ACTION_RANGE 50.0f
#define MAX_VEL 20.0f
#define HSTEP 0.1f

__device__ __forceinline__ void mat3_mul(float* C, const float* A, const float* B) {
#pragma unroll
  for (int r = 0; r < 3; r++) {
#pragma unroll
    for (int c = 0; c < 3; c++) {
      C[r*3+c] = A[r*3+0]*B[0*3+c] + A[r*3+1]*B[1*3+c] + A[r*3+2]*B[2*3+c];
    }
  }
}

__device__ __forceinline__ void mat3_vec(float* y, const float* A, const float* x) {
#pragma unroll
  for (int r = 0; r < 3; r++)
    y[r] = A[r*3+0]*x[0] + A[r*3+1]*x[1] + A[r*3+2]*x[2];
}

__device__ __forceinline__ void mat3T_vec(float* y, const float* A, const float* x) {
#pragma unroll
  for (int r = 0; r < 3; r++)
    y[r] = A[0*3+r]*x[0] + A[1*3+r]*x[1] + A[2*3+r]*x[2];
}

__device__ __forceinline__ void cross3(float* y, const float* a, const float* b) {
  y[0] = a[1]*b[2] - a[2]*b[1];
  y[1] = a[2]*b[0] - a[0]*b[2];
  y[2] = a[0]*b[1] - a[1]*b[0];
}

// R = I + s*W + (1-c)*W^2 ; p = (th*I + (1-c)*W + (th-s)*W^2) v
__device__ __forceinline__ void exp_se3(const float* A6, float th, float* R, float* p) {
  float w0 = A6[0], w1 = A6[1], w2 = A6[2];
  float s, c;
  sincosf(th, &s, &c);
  float omc = 1.0f - c, tms = th - s;
  float W[9]  = {0.f, -w2, w1,  w2, 0.f, -w0,  -w1, w0, 0.f};
  float W2[9];
  mat3_mul(W2, W, W);
#pragma unroll
  for (int k = 0; k < 9; k++) R[k] = s*W[k] + omc*W2[k];
  R[0] += 1.f; R[4] += 1.f; R[8] += 1.f;
  float G[9];
#pragma unroll
  for (int k = 0; k < 9; k++) G[k] = omc*W[k] + tms*W2[k];
  G[0] += th; G[4] += th; G[8] += th;
  mat3_vec(p, G, A6 + 3);
}

// python-style mod: a - floor(a/y)*y  (result in [0,y))
__device__ __forceinline__ float wrap_pi(float x) {
  const float PI_F   = 3.14159265358979323846f;
  const float TWO_PI = 6.28318530717958647692f;
  float a = x + PI_F;
  float r = a - floorf(a * (1.0f / TWO_PI)) * TWO_PI;
  return r - PI_F;
}

// 8 lanes per element: role r = lane&7, element slot e = lane>>3.
// R4 post-mortem: lane-7's in-register V/Vd history (84 floats) pushed that
// branch past the 128-VGPR tier -> compiler spilled -> 214 MB/dispatch scratch
// HBM traffic. R5: history goes to LDS (sVV), same as sRB. 8 active lanes with
// distinct e hit distinct banks -> conflict-free.
__global__ __launch_bounds__(BLOCK, 2) void arm_rk4_kernel(
    const float* __restrict__ g_state, const float* __restrict__ g_action,
    const float* __restrict__ g_M, const float* __restrict__ g_A,
    const float* __restrict__ g_G, const float* __restrict__ g_grav,
    float* __restrict__ g_out_state, float* __restrict__ g_out_ee)
{
  __shared__ float sMR[8][9];
  __shared__ float sMp[8][3];
  __shared__ float sIR[7][9];
  __shared__ float sIp[7][3];
  __shared__ float sA[7][6];
  __shared__ float sG[7][4];
  __shared__ float sg[3];
  __shared__ float sRB[7*18*EP];   // per joint: R[9], B[9]  (AdT = [[R,0],[B,R]])
  __shared__ float sVV[7*12*EP];   // per joint: Vw,Vv,Dw,Dv (bias sweep history)
  __shared__ float tauL[NDOF*EP];
  __shared__ float dqsL[NDOF*EP];
  __shared__ float qaccL[NDOF*EP];
  __shared__ float qfL[NDOF*EP];
  __shared__ float MllL[28*EP];

  const int tid = threadIdx.x;
  const int e = tid >> 3;
  const int r = tid & 7;
  const int b = blockIdx.x * EPB + e;

  if (tid < 8) {
    const float* Mi = g_M + tid*16;
    float a1[3] = {Mi[0], Mi[4], Mi[8]};
    float a2[3] = {Mi[1], Mi[5], Mi[9]};
    float p[3]  = {Mi[3], Mi[7], Mi[11]};
    float n1 = sqrtf(a1[0]*a1[0] + a1[1]*a1[1] + a1[2]*a1[2]);
    float b1[3] = {a1[0]/n1, a1[1]/n1, a1[2]/n1};
    float d = a2[0]*b1[0] + a2[1]*b1[1] + a2[2]*b1[2];
    float a2o[3] = {a2[0]-d*b1[0], a2[1]-d*b1[1], a2[2]-d*b1[2]};
    float n2 = sqrtf(a2o[0]*a2o[0] + a2o[1]*a2o[1] + a2o[2]*a2o[2]);
    float b2[3] = {a2o[0]/n2, a2o[1]/n2, a2o[2]/n2};
    float b3[3];
    cross3(b3, b1, b2);
    float R[9] = {b1[0], b2[0], b3[0],  b1[1], b2[1], b3[1],  b1[2], b2[2], b3[2]};
#pragma unroll
    for (int k = 0; k < 9; k++) sMR[tid][k] = R[k];
    sMp[tid][0] = p[0]; sMp[tid][1] = p[1]; sMp[tid][2] = p[2];
    if (tid < 7) {
#pragma unroll
      for (int rr = 0; rr < 3; rr++)
#pragma unroll
        for (int cc = 0; cc < 3; cc++) sIR[tid][rr*3+cc] = R[cc*3+rr];
#pragma unroll
      for (int rr = 0; rr < 3; rr++)
        sIp[tid][rr] = -(R[0*3+rr]*p[0] + R[1*3+rr]*p[1] + R[2*3+rr]*p[2]);
      const float* Ar = g_A + tid*6;
      float nw = sqrtf(Ar[0]*Ar[0] + Ar[1]*Ar[1] + Ar[2]*Ar[2]);
      sA[tid][0] = Ar[0]/nw; sA[tid][1] = Ar[1]/nw; sA[tid][2] = Ar[2]/nw;
      sA[tid][3] = Ar[3];    sA[tid][4] = Ar[4];    sA[tid][5] = Ar[5];
      sG[tid][0] = fabsf(g_G[tid*4+0]);
      sG[tid][1] = fabsf(g_G[tid*4+1]);
      sG[tid][2] = fabsf(g_G[tid*4+2]);
      sG[tid][3] = fabsf(g_G[tid*4+3]);
    }
  }
  if (tid == 0) { sg[0] = g_grav[0]; sg[1] = g_grav[1]; sg[2] = g_grav[2]; }

  float q0 = 0.f, dq0 = 0.f, tau = 0.f, qs = 0.f, dqs = 0.f;
  float accq = 0.f, accd = 0.f;
  if (r < NDOF) {
    q0  = g_state[b*14 + r];
    dq0 = g_state[b*14 + 7 + r];
    tau = g_action[b*7 + r] * ACTION_RANGE;
    qs = q0; dqs = dq0;
    tauL[r*EP + e] = tau;
    dqsL[r*EP + e] = dq0;
  }
  __syncthreads();

#pragma unroll 1
  for (int st = 0; st < 4; st++) {
    float bias_reg[NDOF];   // r==7 lanes: carried B -> D within this stage

    // ---- (A) adjoint of joint r, lanes r<7 ----
    if (r < NDOF) {
      const int i = r;
      float Ai[6];
#pragma unroll
      for (int k = 0; k < 6; k++) Ai[k] = sA[i][k];
      float Re[9], pe[3];
      exp_se3(Ai, -qs, Re, pe);
      float IRl[9];
#pragma unroll
      for (int k = 0; k < 9; k++) IRl[k] = sIR[i][k];
      float Tr9[9];
      mat3_mul(Tr9, Re, IRl);
      float Ipl[3] = {sIp[i][0], sIp[i][1], sIp[i][2]};
      float Tp[3];
      mat3_vec(Tp, Re, Ipl);
      Tp[0] += pe[0]; Tp[1] += pe[1]; Tp[2] += pe[2];
      float Bm[9];
#pragma unroll
      for (int c = 0; c < 3; c++) {
        Bm[0*3+c] = -Tp[2]*Tr9[1*3+c] + Tp[1]*Tr9[2*3+c];
        Bm[1*3+c] =  Tp[2]*Tr9[0*3+c] - Tp[0]*Tr9[2*3+c];
        Bm[2*3+c] = -Tp[1]*Tr9[0*3+c] + Tp[0]*Tr9[1*3+c];
      }
#pragma unroll
      for (int k = 0; k < 9; k++) {
        sRB[(i*18 +     k)*EP + e] = Tr9[k];
        sRB[(i*18 + 9 + k)*EP + e] = Bm[k];
      }
    }
    __syncthreads();

    // ---- (B) bias sweep, lane r==7 (history in LDS, not registers) ----
    if (r == NDOF) {
      float Vw[3] = {0,0,0}, Vv[3] = {0,0,0};
      float Dw[3] = {0,0,0}, Dv[3] = {-sg[0], -sg[1], -sg[2]};
#pragma unroll
      for (int i = 0; i < NDOF; i++) {
        float R[9], Bm[9];
#pragma unroll
        for (int k = 0; k < 9; k++) {
          R[k]  = sRB[(i*18 +     k)*EP + e];
          Bm[k] = sRB[(i*18 + 9 + k)*EP + e];
        }
        float tw[3], tv[3], t2[3];
        mat3_vec(tw, R, Vw);
        mat3_vec(tv, Bm, Vw);
        mat3_vec(t2, R, Vv);
        tv[0] += t2[0]; tv[1] += t2[1]; tv[2] += t2[2];
        float Aw[3] = {sA[i][0], sA[i][1], sA[i][2]};
        float Av[3] = {sA[i][3], sA[i][4], sA[i][5]};
        float dqi = dqsL[i*EP + e];
#pragma unroll
        for (int k = 0; k < 3; k++) { Vw[k] = tw[k] + Aw[k]*dqi; Vv[k] = tv[k] + Av[k]*dqi; }
        mat3_vec(tw, R, Dw);
        mat3_vec(tv, Bm, Dw);
        mat3_vec(t2, R, Dv);
        tv[0] += t2[0]; tv[1] += t2[1]; tv[2] += t2[2];
        float c1[3], c2[3], c3[3];
        cross3(c1, Vw, Aw);
        cross3(c2, Vv, Aw);
        cross3(c3, Vw, Av);
#pragma unroll
        for (int k = 0; k < 3; k++) { Dw[k] = tw[k] + c1[k]*dqi; Dv[k] = tv[k] + (c2[k]+c3[k])*dqi; }
#pragma unroll
        for (int k = 0; k < 3; k++) {
          sVV[(i*12 +     k)*EP + e] = Vw[k];
          sVV[(i*12 + 3 + k)*EP + e] = Vv[k];
          sVV[(i*12 + 6 + k)*EP + e] = Dw[k];
          sVV[(i*12 + 9 + k)*EP + e] = Dv[k];
        }
      }
      float Fw[3] = {0,0,0}, Fv[3] = {0,0,0};
#pragma unroll
      for (int ii = NDOF-1; ii >= 0; ii--) {
        if (ii < NDOF-1) {
          const int j = ii + 1;
          float R[9], Bm[9];
#pragma unroll
          for (int k = 0; k < 9; k++) {
            R[k]  = sRB[(j*18 +     k)*EP + e];
            Bm[k] = sRB[(j*18 + 9 + k)*EP + e];
          }
          float nw[3], nv[3], t[3];
          mat3T_vec(nw, R, Fw);
          mat3T_vec(t, Bm, Fv);
          nw[0] += t[0]; nw[1] += t[1]; nw[2] += t[2];
          mat3T_vec(nv, R, Fv);
          Fw[0] = nw[0]; Fw[1] = nw[1]; Fw[2] = nw[2];
          Fv[0] = nv[0]; Fv[1] = nv[1]; Fv[2] = nv[2];
        }
        float Vwl[3], Vvl[3], Dwl[3], Dvl[3];
#pragma unroll
        for (int k = 0; k < 3; k++) {
          Vwl[k] = sVV[(ii*12 +     k)*EP + e];
          Vvl[k] = sVV[(ii*12 + 3 + k)*EP + e];
          Dwl[k] = sVV[(ii*12 + 6 + k)*EP + e];
          Dvl[k] = sVV[(ii*12 + 9 + k)*EP + e];
        }
        float gx = sG[ii][0], gy = sG[ii][1], gz = sG[ii][2], m = sG[ii][3];
        float GVw[3] = {gx*Vwl[0], gy*Vwl[1], gz*Vwl[2]};
        float GVv[3] = {m*Vvl[0],  m*Vvl[1],  m*Vvl[2]};
        float GDw[3] = {gx*Dwl[0], gy*Dwl[1], gz*Dwl[2]};
        float GDv[3] = {m*Dvl[0],  m*Dvl[1],  m*Dvl[2]};
        float c1[3], c2[3], c3[3];
        cross3(c1, Vwl, GVw);
        cross3(c2, Vvl, GVv);
        cross3(c3, Vwl, GVv);
#pragma unroll
        for (int k = 0; k < 3; k++) { Fw[k] += GDw[k] + c1[k] + c2[k]; Fv[k] += GDv[k] + c3[k]; }
        bias_reg[ii] = Fw[0]*sA[ii][0] + Fw[1]*sA[ii][1] + Fw[2]*sA[ii][2]
                     + Fv[0]*sA[ii][3] + Fv[1]*sA[ii][4] + Fv[2]*sA[ii][5];
      }
    }

    // ---- (C) mass-matrix column r, lanes r<7 ----
    if (r < NDOF) {
      float Ajw[3] = {sA[r][0], sA[r][1], sA[r][2]};
      float Ajv[3] = {sA[r][3], sA[r][4], sA[r][5]};
      float Xw[NDOF][3], Xv[NDOF][3];
#pragma unroll
      for (int k = 0; k < 3; k++) {
        Xw[0][k] = (r == 0) ? Ajw[k] : 0.f;
        Xv[0][k] = (r == 0) ? Ajv[k] : 0.f;
      }
#pragma unroll
      for (int i = 1; i < NDOF; i++) {
        float R[9], Bm[9];
#pragma unroll
        for (int k = 0; k < 9; k++) {
          R[k]  = sRB[(i*18 +     k)*EP + e];
          Bm[k] = sRB[(i*18 + 9 + k)*EP + e];
        }
        float tw[3], tv[3], t2[3];
        mat3_vec(tw, R,  Xw[i-1]);
        mat3_vec(tv, Bm, Xw[i-1]);
        mat3_vec(t2, R,  Xv[i-1]);
#pragma unroll
        for (int k = 0; k < 3; k++) {
          float w_ = tw[k];
          float v_ = tv[k] + t2[k];
          Xw[i][k] = (i == r) ? Ajw[k] : w_;
          Xv[i][k] = (i == r) ? Ajv[k] : v_;
        }
      }
      float Fw[3] = {0,0,0}, Fv[3] = {0,0,0};
#pragma unroll
      for (int i = NDOF-1; i >= 0; i--) {
        if (i < NDOF-1) {
          const int jn = i + 1;
          float R[9], Bm[9];
#pragma unroll
          for (int k = 0; k < 9; k++) {
            R[k]  = sRB[(jn*18 +     k)*EP + e];
            Bm[k] = sRB[(jn*18 + 9 + k)*EP + e];
          }
          float nw[3], nv[3], t[3];
          mat3T_vec(nw, R, Fw);
          mat3T_vec(t, Bm, Fv);
          nw[0] += t[0]; nw[1] += t[1]; nw[2] += t[2];
          mat3T_vec(nv, R, Fv);
          Fw[0] = nw[0]; Fw[1] = nw[1]; Fw[2] = nw[2];
          Fv[0] = nv[0]; Fv[1] = nv[1]; Fv[2] = nv[2];
        }
        Fw[0] += sG[i][0]*Xw[i][0]; Fw[1] += sG[i][1]*Xw[i][1]; Fw[2] += sG[i][2]*Xw[i][2];
        Fv[0] += sG[i][3]*Xv[i][0]; Fv[1] += sG[i][3]*Xv[i][1]; Fv[2] += sG[i][3]*Xv[i][2];
        float Mij = Fw[0]*sA[i][0] + Fw[1]*sA[i][1] + Fw[2]*sA[i][2]
                  + Fv[0]*sA[i][3] + Fv[1]*sA[i][4] + Fv[2]*sA[i][5];
        if (i >= r) MllL[(i*(i+1)/2 + r)*EP + e] = Mij;
      }
    }
    __syncthreads();

    // ---- (D) Cholesky solve, lane r==7 ----
    if (r == NDOF) {
      float Lm[28];
#pragma unroll
      for (int idx = 0; idx < 28; idx++) Lm[idx] = MllL[idx*EP + e];
      float y[NDOF];
#pragma unroll
      for (int i = 0; i < NDOF; i++) y[i] = tauL[i*EP + e] - bias_reg[i];
#pragma unroll
      for (int k = 0; k < NDOF; k++) {
        float d = Lm[k*(k+1)/2 + k];
#pragma unroll
        for (int m2 = 0; m2 < k; m2++) { float l = Lm[k*(k+1)/2 + m2]; d -= l*l; }
        d = sqrtf(d);
        Lm[k*(k+1)/2 + k] = d;
        float inv = 1.0f / d;
#pragma unroll
        for (int i = k+1; i < NDOF; i++) {
          float s = Lm[i*(i+1)/2 + k];
#pragma unroll
          for (int m2 = 0; m2 < k; m2++) s -= Lm[i*(i+1)/2 + m2]*Lm[k*(k+1)/2 + m2];
          Lm[i*(i+1)/2 + k] = s * inv;
        }
      }
#pragma unroll
      for (int i = 0; i < NDOF; i++) {
        float s = y[i];
#pragma unroll
        for (int m2 = 0; m2 < i; m2++) s -= Lm[i*(i+1)/2 + m2]*y[m2];
        y[i] = s / Lm[i*(i+1)/2 + i];
      }
      float qac[NDOF];
#pragma unroll
      for (int i = NDOF-1; i >= 0; i--) {
        float s = y[i];
#pragma unroll
        for (int m2 = i+1; m2 < NDOF; m2++) s -= Lm[m2*(m2+1)/2 + i]*qac[m2];
        qac[i] = s / Lm[i*(i+1)/2 + i];
      }
#pragma unroll
      for (int i = 0; i < NDOF; i++) qaccL[i*EP + e] = qac[i];
    }
    __syncthreads();

    // ---- (E) RK4 stage update, lanes r<7 ----
    if (r < NDOF) {
      float a = qaccL[r*EP + e];
      float w = (st == 0 || st == 3) ? 1.0f : 2.0f;
      accq += w * dqs;
      accd += w * a;
      if (st < 3) {
        float c = (st == 2) ? HSTEP : 0.5f*HSTEP;
        qs  = q0  + c * dqs;
        dqs = dq0 + c * a;
        dqsL[r*EP + e] = dqs;
      }
    }
    // no barrier needed: next stage's post-(A) barrier orders dqsL (E write ->
    // B read) and qaccL (E read -> next D write); sRB/sVV WAR is covered by
    // the post-(C) barrier before this stage's D.
  }

  const float h6 = HSTEP / 6.0f;
  if (r < NDOF) {
    float qf = wrap_pi(q0 + h6*accq);
    float v  = dq0 + h6*accd;
    float dqf = fminf(fmaxf(v, -MAX_VEL), MAX_VEL);
    qfL[r*EP + e] = qf;
    g_out_state[b*14 + r]     = qf;
    g_out_state[b*14 + 7 + r] = dqf;
  }
  __syncthreads();

  if (r == NDOF) {
    float Tr9[9] = {1,0,0, 0,1,0, 0,0,1};
    float Tp[3] = {0,0,0};
#pragma unroll
    for (int i = 0; i < NDOF; i++) {
      float MRl[9];
#pragma unroll
      for (int k = 0; k < 9; k++) MRl[k] = sMR[i][k];
      float Mpl[3] = {sMp[i][0], sMp[i][1], sMp[i][2]};
      float R1[9];
      mat3_mul(R1, Tr9, MRl);
      float p1[3];
      mat3_vec(p1, Tr9, Mpl);
      p1[0] += Tp[0]; p1[1] += Tp[1]; p1[2] += Tp[2];
      float Ai[6];
#pragma unroll
      for (int k = 0; k < 6; k++) Ai[k] = sA[i][k];
      float Re[9], pe[3];
      exp_se3(Ai, qfL[i*EP + e], Re, pe);
      mat3_mul(Tr9, R1, Re);
      mat3_vec(Tp, R1, pe);
      Tp[0] += p1[0]; Tp[1] += p1[1]; Tp[2] += p1[2];
    }
    float Mp7[3] = {sMp[7][0], sMp[7][1], sMp[7][2]};
    float pf[3];
    mat3_vec(pf, Tr9, Mp7);
    g_out_ee[b*2 + 0] = pf[0] + Tp[0];
    g_out_ee[b*2 + 1] = pf[1] + Tp[1];
  }
}

extern "C" void kernel_launch(void* const* d_in, const int* in_sizes, int n_in,
                              void* d_out, int out_size, void* d_ws, size_t ws_size,
                              hipStream_t stream) {
  const float* state  = (const float*)d_in[0];  // (16384,14)
  const float* action = (const float*)d_in[1];  // (16384,7)
  const float* M      = (const float*)d_in[2];  // (8,4,4)
  const float* A      = (const float*)d_in[3];  // (7,6)
  const float* G      = (const float*)d_in[4];  // (7,4)
  const float* grav   = (const float*)d_in[5];  // (3,)
  float* out_state = (float*)d_out;                       // (16384,14)
  float* out_ee    = (float*)d_out + (size_t)BATCH * 14;  // (16384,2)

  arm_rk4_kernel<<<BATCH / EPB, BLOCK, 0, stream>>>(
      state, action, M, A, G, grav, out_state, out_ee);
}